// Round 16
// baseline (5921.063 us; speedup 1.0000x reference)
//
#include <hip/hip_runtime.h>
#include <stdint.h>
#include <math.h>

#define NB 512
#define NS 200
#define NH 128
#define NH3 384
#define NT 1024
#define NWAVE 16

// 2*log2(e): energies prefolded into log2 domain so exp2f = bare v_exp_f32
#define SC2 2.8853900817779268f

// padded LDS index maps (break half-offset bank aliasing) — validated r9/r10
#define IDX4(h) ((h) + (((h) >> 6) << 2))    // float4: +4 per 64
#define IDX1(h) ((h) + (((h) >> 6) << 4))    // float:  +16 per 64

// ---------------- XLA-exact scalar helpers (GRU gate path only) ----------------
__device__ __forceinline__ float xla_tanhf(float x) {
  float cx = fminf(fmaxf(x, -9.0f), 9.0f);
  float x2 = __fmul_rn(cx, cx);
  float p = -2.76076847742355e-16f;
  p = __fadd_rn(__fmul_rn(x2, p), 2.00018790482477e-13f);
  p = __fadd_rn(__fmul_rn(x2, p), -8.60467152213735e-11f);
  p = __fadd_rn(__fmul_rn(x2, p), 5.12229709037114e-08f);
  p = __fadd_rn(__fmul_rn(x2, p), 1.48572235717979e-05f);
  p = __fadd_rn(__fmul_rn(x2, p), 6.37261928875436e-04f);
  p = __fadd_rn(__fmul_rn(x2, p), 4.89352455891786e-03f);
  p = __fmul_rn(cx, p);
  float q = 1.19825839466702e-06f;
  q = __fadd_rn(__fmul_rn(x2, q), 1.18534705686654e-04f);
  q = __fadd_rn(__fmul_rn(x2, q), 2.26843463243900e-03f);
  q = __fadd_rn(__fmul_rn(x2, q), 4.89352518554385e-03f);
  float r = __fdiv_rn(p, q);
  return (fabsf(x) < 0.0004f) ? x : r;
}

__device__ __forceinline__ float xla_sigmoidf(float x) {
  return __fadd_rn(0.5f, __fmul_rn(0.5f, xla_tanhf(__fmul_rn(0.5f, x))));
}

__device__ __forceinline__ uint32_t rotl32(uint32_t v, int r) {
  return (v << r) | (v >> (32 - r));
}
__device__ __forceinline__ void threefry2x32(uint32_t k0, uint32_t k1,
                                             uint32_t x0, uint32_t x1,
                                             uint32_t& o0, uint32_t& o1) {
  uint32_t k2 = k0 ^ k1 ^ 0x1BD11BDAu;
  x0 += k0; x1 += k1;
  #define TFR(r) { x0 += x1; x1 = rotl32(x1, r); x1 ^= x0; }
  TFR(13) TFR(15) TFR(26) TFR(6)
  x0 += k1; x1 += k2 + 1u;
  TFR(17) TFR(29) TFR(16) TFR(24)
  x0 += k2; x1 += k0 + 2u;
  TFR(13) TFR(15) TFR(26) TFR(6)
  x0 += k0; x1 += k1 + 3u;
  TFR(17) TFR(29) TFR(16) TFR(24)
  x0 += k1; x1 += k2 + 4u;
  TFR(13) TFR(15) TFR(26) TFR(6)
  x0 += k2; x1 += k0 + 5u;
  #undef TFR
  o0 = x0; o1 = x1;
}

__device__ __forceinline__ float bits_to_gumbel(uint32_t bits) {
  const float kTiny = 1.1754943508222875e-38f;
  float f = __fsub_rn(__uint_as_float((bits >> 9) | 0x3F800000u), 1.0f);
  float u = __fadd_rn(__fmul_rn(f, __fsub_rn(1.0f, kTiny)), kTiny);
  u = fmaxf(kTiny, u);
  return -logf(-logf(u));
}

// ---------------- persistent kernel: 2 rows/block, 1024 threads --------------
// waves 0-7: row A = blockIdx.x ; waves 8-15: row B = blockIdx.x + 256
// Phases/step (7 barriers): S1 gi/gh shared | S2 gates | S3 Ht | E attn |
//                           F ct | G dec+sample | A winner+next-emb+next-gum
__global__ __launch_bounds__(NT, 4) void k_decode(
    const float* __restrict__ stat, const float* __restrict__ dyn,
    const float* __restrict__ sW,   const float* __restrict__ sb,
    const float* __restrict__ dW,   const float* __restrict__ db,
    const float* __restrict__ x0,   const float* __restrict__ h0,
    const float* __restrict__ Wemb, const float* __restrict__ bemb,
    const float* __restrict__ Wih,  const float* __restrict__ Whh,
    const float* __restrict__ bih,  const float* __restrict__ bhh,
    const float* __restrict__ Wa,   const float* __restrict__ va,
    const float* __restrict__ Wd,   const float* __restrict__ vd,
    float* __restrict__ out) {

  __shared__ __align__(16) float st0A[NS], st1A[NS], dy0A[NS], dy1A[NS];
  __shared__ __align__(16) float st0B[NS], st1B[NS], dy0B[NS], dy1B[NS];
  __shared__ float4 AF4p[132];             // SC2*{As0,As1,Ad0,Ad1} padded
  __shared__ float4 DFSp[132];             // {SC2*Ds0,SC2*Ds1,vd,0} padded
  __shared__ float4 CW4[NH];               // SC2*{Cw0,Cw1,Cwb,Dc}
  __shared__ float  vaP[144];              // va padded
  __shared__ float  Ht2A[144], Ht2B[144];  // SC2*(Ht+Ac) per row, padded
  __shared__ float  ct2A[144], ct2B[144];  // SC2*(ct+Dc) per row, padded
  __shared__ float  AcL[NH];
  __shared__ float WembL[2*NH], bembL[NH];
  __shared__ float bihL[NH3], bhhL[NH3];
  __shared__ __align__(16) float embA[NH], embB[NH], hA[NH], hB[NH];
  __shared__ float giA[NH3], ghA[NH3], giB[NH3], ghB[NH3];
  __shared__ float ex2A[NS], ex2B[NS], gumA[NS], gumB[NS];
  __shared__ uint32_t keysL[2*NS];
  __shared__ float SvL[2];
  __shared__ float part[NWAVE][8];
  __shared__ int   partI[NWAVE];

  const int t = threadIdx.x;
  const int bA = blockIdx.x;
  const int bB = blockIdx.x + 256;
  const int w = t >> 6;                    // global wave 0..15
  const bool rB = (t >= 512);
  const int tr = rB ? (t - 512) : t;       // intra-row lane 0..511
  const int s = tr >> 1;                   // candidate node (lane pairs)
  const int h0i = (tr & 1) * 64;
  const int b4 = h0i + ((h0i >> 6) << 2);
  const int b1 = h0i + ((h0i >> 6) << 4);
  const bool act = (tr < 2*NS);            // 400 task lanes per row

  // ---- one-time setup ----
  if (t < NS) {
    st0A[t] = stat[(size_t)bA*2*NS + t];
    st1A[t] = stat[(size_t)bA*2*NS + NS + t];
    dy0A[t] = dyn[(size_t)bA*2*NS + t];
    dy1A[t] = dyn[(size_t)bA*2*NS + NS + t];
    uint32_t q0, q1;
    threefry2x32(0u, 42u, 0u, (uint32_t)t, q0, q1);
    keysL[2*t] = q0; keysL[2*t + 1] = q1;
  } else if (t >= 256 && t < 256 + NS) {
    int si = t - 256;
    st0B[si] = stat[(size_t)bB*2*NS + si];
    st1B[si] = stat[(size_t)bB*2*NS + NS + si];
    dy0B[si] = dyn[(size_t)bB*2*NS + si];
    dy1B[si] = dyn[(size_t)bB*2*NS + NS + si];
  }
  if (t >= 512 && t < 512 + NH) {
    int h = t - 512;
    const float* war = Wa + (size_t)h * NH3;
    float as0 = 0.f, as1 = 0.f, ad0 = 0.f, ad1 = 0.f, ac = 0.f;
    for (int k = 0; k < NH; ++k) {
      as0 = fmaf(war[k],     sW[k*2+0], as0);
      as1 = fmaf(war[k],     sW[k*2+1], as1);
      ad0 = fmaf(war[NH+k],  dW[k*2+0], ad0);
      ad1 = fmaf(war[NH+k],  dW[k*2+1], ad1);
      ac  = fmaf(war[k],     sb[k],     ac);
    }
    for (int k = 0; k < NH; ++k) ac = fmaf(war[NH+k], db[k], ac);
    AF4p[IDX4(h)] = make_float4(SC2*as0, SC2*as1, SC2*ad0, SC2*ad1);
    vaP[IDX1(h)] = va[h];
    AcL[h] = ac;

    const float* wdr = Wd + (size_t)h * 256;
    float ds0 = 0.f, ds1 = 0.f, dc = 0.f, c0 = 0.f, c1 = 0.f, cb = 0.f;
    for (int k = 0; k < NH; ++k) {
      ds0 = fmaf(wdr[k],    sW[k*2+0], ds0);
      ds1 = fmaf(wdr[k],    sW[k*2+1], ds1);
      dc  = fmaf(wdr[k],    sb[k],     dc);
      c0  = fmaf(wdr[NH+k], sW[k*2+0], c0);
      c1  = fmaf(wdr[NH+k], sW[k*2+1], c1);
      cb  = fmaf(wdr[NH+k], sb[k],     cb);
    }
    DFSp[IDX4(h)] = make_float4(SC2*ds0, SC2*ds1, vd[h], 0.f);
    CW4[h] = make_float4(SC2*c0, SC2*c1, SC2*cb, SC2*dc);

    bembL[h] = bemb[h];
    WembL[2*h]   = Wemb[2*h];
    WembL[2*h+1] = Wemb[2*h+1];
    hA[h] = h0[h];
    hB[h] = h0[h];
  }
  for (int i = t; i < NH3; i += NT) { bihL[i] = bih[i]; bhhL[i] = bhh[i]; }
  if (t == 0) {
    float sva = 0.f, svd = 0.f;
    for (int h = 0; h < NH; ++h) { sva = __fadd_rn(sva, va[h]); svd = __fadd_rn(svd, vd[h]); }
    SvL[0] = sva; SvL[1] = svd;
  }
  __syncthreads();

  // setup 2: initial emb (x0), initial gumbels (step 0), hoist per-s regs
  if (t < NH) {
    float e = fmaf(x0[1], WembL[t*2+1], __fmul_rn(x0[0], WembL[t*2+0]));
    embA[t] = __fadd_rn(e, bembL[t]);
  } else if (t < 2*NH) {
    int h = t - NH;
    float e = fmaf(x0[1], WembL[h*2+1], __fmul_rn(x0[0], WembL[h*2+0]));
    embB[h] = __fadd_rn(e, bembL[h]);
  } else if (t >= 624) {
    int gi = t - 624;                      // 0..399
    uint32_t q0, q1;
    if (gi < NS) {
      threefry2x32(keysL[0], keysL[1], 0u, (uint32_t)(bA*NS + gi), q0, q1);
      gumA[gi] = bits_to_gumbel(q0 ^ q1);
    } else {
      int si = gi - NS;
      threefry2x32(keysL[0], keysL[1], 0u, (uint32_t)(bB*NS + si), q0, q1);
      gumB[si] = bits_to_gumbel(q0 ^ q1);
    }
  }
  float s0r = 0.f, s1r = 0.f, d0r = 0.f, d1r = 0.f;
  if (act) {
    if (!rB) { s0r = st0A[s]; s1r = st1A[s]; d0r = dy0A[s]; d1r = dy1A[s]; }
    else     { s0r = st0B[s]; s1r = st1B[s]; d0r = dy0B[s]; d1r = dy1B[s]; }
  }
  const float svaR = SvL[0], svdR = SvL[1];
  const float* HtX = rB ? Ht2B : Ht2A;
  const float* ctX = rB ? ct2B : ct2A;
  const float* gumX = rB ? gumB : gumA;
  __syncthreads();

  // ---- 200 decode steps ----
  for (int step = 0; step < NS; ++step) {
    // S1: 768 weight rows, each loaded once, dots for BOTH rows
    // (per-row sequential-k chain bit-identical to r5-r15)
    if (t < 2*NH3) {
      const bool isWih = (t < NH3);
      const float4* wp = isWih
          ? (const float4*)(Wih + (size_t)t * NH)
          : (const float4*)(Whh + (size_t)(t - NH3) * NH);
      const float4* opA = isWih ? (const float4*)embA : (const float4*)hA;
      const float4* opB = isWih ? (const float4*)embB : (const float4*)hB;
      float aA = 0.f, aB = 0.f;
      #pragma unroll 8
      for (int k4 = 0; k4 < 32; ++k4) {
        float4 c = wp[k4];
        float4 vA = opA[k4], vB = opB[k4];
        aA = fmaf(c.x, vA.x, aA); aA = fmaf(c.y, vA.y, aA);
        aA = fmaf(c.z, vA.z, aA); aA = fmaf(c.w, vA.w, aA);
        aB = fmaf(c.x, vB.x, aB); aB = fmaf(c.y, vB.y, aB);
        aB = fmaf(c.z, vB.z, aB); aB = fmaf(c.w, vB.w, aB);
      }
      if (isWih) {
        giA[t] = __fadd_rn(aA, bihL[t]);
        giB[t] = __fadd_rn(aB, bihL[t]);
      } else {
        int row = t - NH3;
        ghA[row] = __fadd_rn(aA, bhhL[row]);
        ghB[row] = __fadd_rn(aB, bhhL[row]);
      }
    }
    __syncthreads();

    // S2: gates (torch r,z,n) EXACT XLA math; rowA t<128, rowB [128,256)
    if (t < NH) {
      float r = xla_sigmoidf(__fadd_rn(giA[t],      ghA[t]));
      float z = xla_sigmoidf(__fadd_rn(giA[t+NH],   ghA[t+NH]));
      float n = xla_tanhf(__fadd_rn(giA[t+2*NH], __fmul_rn(r, ghA[t+2*NH])));
      float hv = hA[t];
      hA[t] = __fadd_rn(__fmul_rn(__fsub_rn(1.0f, z), n), __fmul_rn(z, hv));
    } else if (t < 2*NH) {
      int h = t - NH;
      float r = xla_sigmoidf(__fadd_rn(giB[h],      ghB[h]));
      float z = xla_sigmoidf(__fadd_rn(giB[h+NH],   ghB[h+NH]));
      float n = xla_tanhf(__fadd_rn(giB[h+2*NH], __fmul_rn(r, ghB[h+2*NH])));
      float hv = hB[h];
      hB[h] = __fadd_rn(__fmul_rn(__fsub_rn(1.0f, z), n), __fmul_rn(z, hv));
    }
    __syncthreads();

    // S3: Hterm per row (exact chain); store SC2*(Ht+Ac)
    if (t < NH) {
      const float4* war = (const float4*)(Wa + (size_t)t*NH3 + 2*NH);
      const float4* hn4 = (const float4*)hA;
      float acc = 0.f;
      #pragma unroll 8
      for (int k4 = 0; k4 < 32; ++k4) {
        float4 a = war[k4], hv = hn4[k4];
        acc = fmaf(a.x, hv.x, acc); acc = fmaf(a.y, hv.y, acc);
        acc = fmaf(a.z, hv.z, acc); acc = fmaf(a.w, hv.w, acc);
      }
      Ht2A[IDX1(t)] = __fmul_rn(SC2, __fadd_rn(acc, AcL[t]));
    } else if (t < 2*NH) {
      int h = t - NH;
      const float4* war = (const float4*)(Wa + (size_t)h*NH3 + 2*NH);
      const float4* hn4 = (const float4*)hB;
      float acc = 0.f;
      #pragma unroll 8
      for (int k4 = 0; k4 < 32; ++k4) {
        float4 a = war[k4], hv = hn4[k4];
        acc = fmaf(a.x, hv.x, acc); acc = fmaf(a.y, hv.y, acc);
        acc = fmaf(a.z, hv.z, acc); acc = fmaf(a.w, hv.w, acc);
      }
      Ht2B[IDX1(h)] = __fmul_rn(SC2, __fadd_rn(acc, AcL[h]));
    }
    __syncthreads();

    // E: attention; log2-domain energies, dual accumulators
    float accE0 = 0.f, accE1 = 0.f;
    if (act) {
      #pragma unroll 4
      for (int j = 0; j < 64; j += 2) {
        float4 af0 = AF4p[b4 + j];
        float e0 = fmaf(af0.x, s0r, HtX[b1 + j]);
        e0 = fmaf(af0.y, s1r, e0);
        e0 = fmaf(af0.z, d0r, e0);
        e0 = fmaf(af0.w, d1r, e0);
        float r0v = __builtin_amdgcn_rcpf(__fadd_rn(exp2f(e0), 1.0f));
        accE0 = fmaf(vaP[b1 + j], r0v, accE0);
        float4 af1 = AF4p[b4 + j + 1];
        float e1 = fmaf(af1.x, s0r, HtX[b1 + j + 1]);
        e1 = fmaf(af1.y, s1r, e1);
        e1 = fmaf(af1.z, d0r, e1);
        e1 = fmaf(af1.w, d1r, e1);
        float r1v = __builtin_amdgcn_rcpf(__fadd_rn(exp2f(e1), 1.0f));
        accE1 = fmaf(vaP[b1 + j + 1], r1v, accE1);
      }
    }
    float accE = __fadd_rn(accE0, accE1);
    float accSum = __fadd_rn(accE, __shfl_xor(accE, 1));
    float sc = act ? fmaf(-2.0f, accSum, svaR) : 0.f;

    float exv = act ? __expf(sc) : 0.f;
    {
      float sm = exv;
      float c0 = __fmul_rn(exv, s0r);
      float c1 = __fmul_rn(exv, s1r);
      #pragma unroll
      for (int mm = 2; mm < 64; mm <<= 1) {
        sm = __fadd_rn(sm, __shfl_xor(sm, mm));
        c0 = __fadd_rn(c0, __shfl_xor(c0, mm));
        c1 = __fadd_rn(c1, __shfl_xor(c1, mm));
      }
      if ((t & 63) == 0) { part[w][0] = sm; part[w][1] = c0; part[w][2] = c1; }
    }
    __syncthreads();

    // F: ct2 per row; rowA from part[0..7], rowB from part[8..15]
    if (t < 2*NH) {
      int h = t & (NH - 1);
      int base = (t < NH) ? 0 : 8;
      float sume = part[base][0], r0 = part[base][1], r1 = part[base][2];
      #pragma unroll
      for (int ww = 1; ww < 8; ++ww) {
        sume = __fadd_rn(sume, part[base + ww][0]);
        r0   = __fadd_rn(r0,   part[base + ww][1]);
        r1   = __fadd_rn(r1,   part[base + ww][2]);
      }
      r0 = __fdiv_rn(r0, sume); r1 = __fdiv_rn(r1, sume);
      float4 cw = CW4[h];
      float ct2 = fmaf(r0, cw.x, fmaf(r1, cw.y, cw.z));
      if (t < NH) ct2A[IDX1(h)] = __fadd_rn(cw.w, ct2);
      else        ct2B[IDX1(h)] = __fadd_rn(cw.w, ct2);
    }
    __syncthreads();

    // G: decoder; log2-domain, dual accumulators; hoisted gumbel
    float accD0 = 0.f, accD1 = 0.f;
    if (act) {
      #pragma unroll 4
      for (int j = 0; j < 64; j += 2) {
        float4 df0 = DFSp[b4 + j];
        float d0 = fmaf(df0.x, s0r, ctX[b1 + j]);
        d0 = fmaf(df0.y, s1r, d0);
        float r0v = __builtin_amdgcn_rcpf(__fadd_rn(exp2f(d0), 1.0f));
        accD0 = fmaf(df0.z, r0v, accD0);
        float4 df1 = DFSp[b4 + j + 1];
        float d1 = fmaf(df1.x, s0r, ctX[b1 + j + 1]);
        d1 = fmaf(df1.y, s1r, d1);
        float r1v = __builtin_amdgcn_rcpf(__fadd_rn(exp2f(d1), 1.0f));
        accD1 = fmaf(df1.z, r1v, accD1);
      }
    }
    float accD = __fadd_rn(accD0, accD1);
    float accDS = __fadd_rn(accD, __shfl_xor(accD, 1));
    float sc2 = act ? fmaf(-2.0f, accDS, svdR) : 0.f;

    float e2v = act ? __expf(sc2) : 0.f;
    if (act && (tr & 1) == 0) { if (!rB) ex2A[s] = e2v; else ex2B[s] = e2v; }
    {
      float gv = -INFINITY;
      int gidx = 1 << 20;
      if (act) {
        gv = __fadd_rn(gumX[s], sc2);
        gidx = s;
      }
      float sm = e2v;
      #pragma unroll
      for (int mm = 2; mm < 64; mm <<= 1) {
        sm = __fadd_rn(sm, __shfl_xor(sm, mm));
        float ov = __shfl_xor(gv, mm); int oi = __shfl_xor(gidx, mm);
        if (ov > gv || (ov == gv && oi < gidx)) { gv = ov; gidx = oi; }
      }
      if ((t & 63) == 0) { part[w][3] = sm; part[w][4] = gv; partI[w] = gidx; }
    }
    __syncthreads();

    // A (merged with next-step S0): winner combine on t<256; next emb;
    // next gumbels on t>=624
    if (t < 2*NH) {
      int base = (t < NH) ? 0 : 8;
      float bv = part[base][4]; int bi = partI[base];
      float sume2 = part[base][3];
      #pragma unroll
      for (int ww = 1; ww < 8; ++ww) {
        float vv = part[base + ww][4]; int ii = partI[base + ww];
        if (vv > bv || (vv == bv && ii < bi)) { bv = vv; bi = ii; }
        sume2 = __fadd_rn(sume2, part[base + ww][3]);
      }
      if (t == 0) {
        out[(size_t)bA*NS + step] = (float)bi;
        out[(size_t)NB*NS + (size_t)bA*NS + step] = __fdiv_rn(ex2A[bi], sume2);
      } else if (t == NH) {
        out[(size_t)bB*NS + step] = (float)bi;
        out[(size_t)NB*NS + (size_t)bB*NS + step] = __fdiv_rn(ex2B[bi], sume2);
      }
      // next-step emb (bit-identical chain; xa/xb from winner gather)
      if (t < NH) {
        float xa = st0A[bi], xb = st1A[bi];
        float e = fmaf(xb, WembL[t*2+1], __fmul_rn(xa, WembL[t*2+0]));
        embA[t] = __fadd_rn(e, bembL[t]);
      } else {
        int h = t - NH;
        float xa = st0B[bi], xb = st1B[bi];
        float e = fmaf(xb, WembL[h*2+1], __fmul_rn(xa, WembL[h*2+0]));
        embB[h] = __fadd_rn(e, bembL[h]);
      }
    } else if (t >= 624) {
      int nstep = (step + 1 < NS) ? (step + 1) : step;  // last iter harmless
      int gi = t - 624;
      uint32_t k0 = keysL[2*nstep], k1 = keysL[2*nstep + 1];
      uint32_t q0, q1;
      if (gi < NS) {
        threefry2x32(k0, k1, 0u, (uint32_t)(bA*NS + gi), q0, q1);
        gumA[gi] = bits_to_gumbel(q0 ^ q1);
      } else {
        int si = gi - NS;
        threefry2x32(k0, k1, 0u, (uint32_t)(bB*NS + si), q0, q1);
        gumB[si] = bits_to_gumbel(q0 ^ q1);
      }
    }
    __syncthreads();
  }
}

// ---------------- host launch ----------------
extern "C" void kernel_launch(void* const* d_in, const int* in_sizes, int n_in,
                              void* d_out, int out_size, void* d_ws, size_t ws_size,
                              hipStream_t stream) {
  (void)in_sizes; (void)n_in; (void)out_size; (void)d_ws; (void)ws_size;
  const float* stat = (const float*)d_in[0];
  const float* dyn  = (const float*)d_in[1];
  const float* sW   = (const float*)d_in[2];
  const float* sb   = (const float*)d_in[3];
  const float* dW   = (const float*)d_in[4];
  const float* db   = (const float*)d_in[5];
  const float* x0   = (const float*)d_in[6];
  const float* h0   = (const float*)d_in[7];
  const float* Wemb = (const float*)d_in[8];
  const float* bemb = (const float*)d_in[9];
  const float* Wih  = (const float*)d_in[10];
  const float* Whh  = (const float*)d_in[11];
  const float* bih  = (const float*)d_in[12];
  const float* bhh  = (const float*)d_in[13];
  const float* Wa   = (const float*)d_in[14];
  const float* va   = (const float*)d_in[15];
  const float* Wd   = (const float*)d_in[16];
  const float* vd   = (const float*)d_in[17];
  float* out = (float*)d_out;

  k_decode<<<NB/2, NT, 0, stream>>>(stat, dyn, sW, sb, dW, db, x0, h0,
                                    Wemb, bemb, Wih, Whh, bih, bhh,
                                    Wa, va, Wd, vd, out);
}

// Round 17
// 5419.375 us; speedup vs baseline: 1.0926x; 1.0926x over previous
//
#include <hip/hip_runtime.h>
#include <stdint.h>
#include <math.h>

#define NB 512
#define NS 200
#define NH 128
#define NH3 384
#define NT 1024
#define NWAVE 16

// 2*log2(e): energies prefolded into log2 domain so exp2 = bare v_exp_f32
#define SC2 2.8853900817779268f

// padded LDS index maps (break half-offset bank aliasing) — validated r9/r10
#define IDX4(h) ((h) + (((h) >> 6) << 2))    // float4: +4 per 64
#define IDX2(h) ((h) + (((h) >> 6) << 3))    // float2: +8 per 64
#define IDX1(h) ((h) + (((h) >> 6) << 4))    // float:  +16 per 64

// bare HW exp2 (v_exp_f32); FTZ below 2^-126 is harmless (feeds rcp(x+1))
__device__ __forceinline__ float fexp2(float x) {
#if __has_builtin(__builtin_amdgcn_exp2f)
  return __builtin_amdgcn_exp2f(x);
#else
  return exp2f(x);
#endif
}

// ---------------- XLA-exact scalar helpers (GRU gate path only) ----------------
__device__ __forceinline__ float xla_tanhf(float x) {
  float cx = fminf(fmaxf(x, -9.0f), 9.0f);
  float x2 = __fmul_rn(cx, cx);
  float p = -2.76076847742355e-16f;
  p = __fadd_rn(__fmul_rn(x2, p), 2.00018790482477e-13f);
  p = __fadd_rn(__fmul_rn(x2, p), -8.60467152213735e-11f);
  p = __fadd_rn(__fmul_rn(x2, p), 5.12229709037114e-08f);
  p = __fadd_rn(__fmul_rn(x2, p), 1.48572235717979e-05f);
  p = __fadd_rn(__fmul_rn(x2, p), 6.37261928875436e-04f);
  p = __fadd_rn(__fmul_rn(x2, p), 4.89352455891786e-03f);
  p = __fmul_rn(cx, p);
  float q = 1.19825839466702e-06f;
  q = __fadd_rn(__fmul_rn(x2, q), 1.18534705686654e-04f);
  q = __fadd_rn(__fmul_rn(x2, q), 2.26843463243900e-03f);
  q = __fadd_rn(__fmul_rn(x2, q), 4.89352518554385e-03f);
  float r = __fdiv_rn(p, q);
  return (fabsf(x) < 0.0004f) ? x : r;
}

__device__ __forceinline__ float xla_sigmoidf(float x) {
  return __fadd_rn(0.5f, __fmul_rn(0.5f, xla_tanhf(__fmul_rn(0.5f, x))));
}

__device__ __forceinline__ uint32_t rotl32(uint32_t v, int r) {
  return (v << r) | (v >> (32 - r));
}
__device__ __forceinline__ void threefry2x32(uint32_t k0, uint32_t k1,
                                             uint32_t x0, uint32_t x1,
                                             uint32_t& o0, uint32_t& o1) {
  uint32_t k2 = k0 ^ k1 ^ 0x1BD11BDAu;
  x0 += k0; x1 += k1;
  #define TFR(r) { x0 += x1; x1 = rotl32(x1, r); x1 ^= x0; }
  TFR(13) TFR(15) TFR(26) TFR(6)
  x0 += k1; x1 += k2 + 1u;
  TFR(17) TFR(29) TFR(16) TFR(24)
  x0 += k2; x1 += k0 + 2u;
  TFR(13) TFR(15) TFR(26) TFR(6)
  x0 += k0; x1 += k1 + 3u;
  TFR(17) TFR(29) TFR(16) TFR(24)
  x0 += k1; x1 += k2 + 4u;
  TFR(13) TFR(15) TFR(26) TFR(6)
  x0 += k2; x1 += k0 + 5u;
  #undef TFR
  o0 = x0; o1 = x1;
}

__device__ __forceinline__ float bits_to_gumbel(uint32_t bits) {
  const float kTiny = 1.1754943508222875e-38f;
  float f = __fsub_rn(__uint_as_float((bits >> 9) | 0x3F800000u), 1.0f);
  float u = __fadd_rn(__fmul_rn(f, __fsub_rn(1.0f, kTiny)), kTiny);
  u = fmaxf(kTiny, u);
  return -logf(-logf(u));
}

// ---------------- persistent kernel: 2 rows/block, 1024 threads --------------
// waves 0-7: row A = blockIdx.x ; waves 8-15: row B = blockIdx.x + 256
// S1: t<768 -> weight row t loaded ONCE, dots for BOTH rows (halves L2 stream)
__global__ __launch_bounds__(NT, 4) void k_decode(
    const float* __restrict__ stat, const float* __restrict__ dyn,
    const float* __restrict__ sW,   const float* __restrict__ sb,
    const float* __restrict__ dW,   const float* __restrict__ db,
    const float* __restrict__ x0,   const float* __restrict__ h0,
    const float* __restrict__ Wemb, const float* __restrict__ bemb,
    const float* __restrict__ Wih,  const float* __restrict__ Whh,
    const float* __restrict__ bih,  const float* __restrict__ bhh,
    const float* __restrict__ Wa,   const float* __restrict__ va,
    const float* __restrict__ Wd,   const float* __restrict__ vd,
    float* __restrict__ out) {

  __shared__ __align__(16) float st0A[NS], st1A[NS], dy0A[NS], dy1A[NS];
  __shared__ __align__(16) float st0B[NS], st1B[NS], dy0B[NS], dy1B[NS];
  __shared__ float4 AF4p[132];             // SC2*{As0,As1,Ad0,Ad1} padded
  __shared__ float4 DFSp[132];             // {SC2*Ds0,SC2*Ds1,vd,0} padded
  __shared__ float4 CW4[NH];               // SC2*{Cw0,Cw1,Cwb,Dc}
  __shared__ float2 HtVaA[136], HtVaB[136];// {va, SC2*(Ht+Ac)} per row, padded
  __shared__ float  ct2A[144], ct2B[144];  // SC2*(ct+Dc) per row, padded
  __shared__ float  AcL[NH];
  __shared__ float WembL[2*NH], bembL[NH];
  __shared__ float bihL[NH3], bhhL[NH3];
  __shared__ __align__(16) float embA[NH], embB[NH], hA[NH], hB[NH];
  __shared__ float giA[NH3], ghA[NH3], giB[NH3], ghB[NH3];
  __shared__ float ex2A[NS], ex2B[NS], gumA[NS], gumB[NS];
  __shared__ uint32_t keysL[2*NS];
  __shared__ float xpA[2], xpB[2];
  __shared__ float SvL[2];
  __shared__ float part[NWAVE][8];
  __shared__ int   partI[NWAVE];

  const int t = threadIdx.x;
  const int bA = blockIdx.x;
  const int bB = blockIdx.x + 256;
  const int w = t >> 6;                    // global wave 0..15
  const bool rB = (t >= 512);
  const int tr = rB ? (t - 512) : t;       // intra-row lane 0..511
  const int s = tr >> 1;                   // candidate node (lane pairs)
  const int h0i = (tr & 1) * 64;
  const int b4 = h0i + ((h0i >> 6) << 2);
  const int b2 = h0i + ((h0i >> 6) << 3);
  const int b1 = h0i + ((h0i >> 6) << 4);
  const bool act = (tr < 2*NS);            // 400 task lanes per row

  // ---- one-time setup ----
  if (t < NS) {
    st0A[t] = stat[(size_t)bA*2*NS + t];
    st1A[t] = stat[(size_t)bA*2*NS + NS + t];
    dy0A[t] = dyn[(size_t)bA*2*NS + t];
    dy1A[t] = dyn[(size_t)bA*2*NS + NS + t];
    uint32_t q0, q1;
    threefry2x32(0u, 42u, 0u, (uint32_t)t, q0, q1);
    keysL[2*t] = q0; keysL[2*t + 1] = q1;
  } else if (t >= 256 && t < 256 + NS) {
    int si = t - 256;
    st0B[si] = stat[(size_t)bB*2*NS + si];
    st1B[si] = stat[(size_t)bB*2*NS + NS + si];
    dy0B[si] = dyn[(size_t)bB*2*NS + si];
    dy1B[si] = dyn[(size_t)bB*2*NS + NS + si];
  }
  if (t >= 512 && t < 512 + NH) {
    int h = t - 512;
    const float* war = Wa + (size_t)h * NH3;
    float as0 = 0.f, as1 = 0.f, ad0 = 0.f, ad1 = 0.f, ac = 0.f;
    for (int k = 0; k < NH; ++k) {
      as0 = fmaf(war[k],     sW[k*2+0], as0);
      as1 = fmaf(war[k],     sW[k*2+1], as1);
      ad0 = fmaf(war[NH+k],  dW[k*2+0], ad0);
      ad1 = fmaf(war[NH+k],  dW[k*2+1], ad1);
      ac  = fmaf(war[k],     sb[k],     ac);
    }
    for (int k = 0; k < NH; ++k) ac = fmaf(war[NH+k], db[k], ac);
    AF4p[IDX4(h)] = make_float4(SC2*as0, SC2*as1, SC2*ad0, SC2*ad1);
    HtVaA[IDX2(h)] = make_float2(va[h], 0.f);
    HtVaB[IDX2(h)] = make_float2(va[h], 0.f);
    AcL[h] = ac;

    const float* wdr = Wd + (size_t)h * 256;
    float ds0 = 0.f, ds1 = 0.f, dc = 0.f, c0 = 0.f, c1 = 0.f, cb = 0.f;
    for (int k = 0; k < NH; ++k) {
      ds0 = fmaf(wdr[k],    sW[k*2+0], ds0);
      ds1 = fmaf(wdr[k],    sW[k*2+1], ds1);
      dc  = fmaf(wdr[k],    sb[k],     dc);
      c0  = fmaf(wdr[NH+k], sW[k*2+0], c0);
      c1  = fmaf(wdr[NH+k], sW[k*2+1], c1);
      cb  = fmaf(wdr[NH+k], sb[k],     cb);
    }
    DFSp[IDX4(h)] = make_float4(SC2*ds0, SC2*ds1, vd[h], 0.f);
    CW4[h] = make_float4(SC2*c0, SC2*c1, SC2*cb, SC2*dc);

    bembL[h] = bemb[h];
    WembL[2*h]   = Wemb[2*h];
    WembL[2*h+1] = Wemb[2*h+1];
    hA[h] = h0[h];
    hB[h] = h0[h];
  }
  for (int i = t; i < NH3; i += NT) { bihL[i] = bih[i]; bhhL[i] = bhh[i]; }
  if (t == 0) {
    xpA[0] = x0[0]; xpA[1] = x0[1];
    xpB[0] = x0[0]; xpB[1] = x0[1];
    float sva = 0.f, svd = 0.f;
    for (int h = 0; h < NH; ++h) { sva = __fadd_rn(sva, va[h]); svd = __fadd_rn(svd, vd[h]); }
    SvL[0] = sva; SvL[1] = svd;
  }
  __syncthreads();

  // per-s inputs hoisted (pair-uniform, per row)
  float s0r = 0.f, s1r = 0.f, d0r = 0.f, d1r = 0.f;
  if (act) {
    if (!rB) { s0r = st0A[s]; s1r = st1A[s]; d0r = dy0A[s]; d1r = dy1A[s]; }
    else     { s0r = st0B[s]; s1r = st1B[s]; d0r = dy0B[s]; d1r = dy1B[s]; }
  }
  const float svaR = SvL[0], svdR = SvL[1];
  const float2* HtX = rB ? HtVaB : HtVaA;
  const float* ctX = rB ? ct2B : ct2A;
  const float* gumX = rB ? gumB : gumA;

  // ---- 200 decode steps ----
  for (int step = 0; step < NS; ++step) {
    // S0: embA (t<128) | embB ([128,256)) | 400 gumbels ([256,656))
    if (t < NH) {
      float e = fmaf(xpA[1], WembL[t*2+1], __fmul_rn(xpA[0], WembL[t*2+0]));
      embA[t] = __fadd_rn(e, bembL[t]);
    } else if (t < 2*NH) {
      int h = t - NH;
      float e = fmaf(xpB[1], WembL[h*2+1], __fmul_rn(xpB[0], WembL[h*2+0]));
      embB[h] = __fadd_rn(e, bembL[h]);
    } else if (t < 2*NH + 2*NS) {
      int gi = t - 2*NH;                   // 0..399
      uint32_t k0 = keysL[2*step], k1 = keysL[2*step + 1];
      uint32_t q0, q1;
      if (gi < NS) {
        threefry2x32(k0, k1, 0u, (uint32_t)(bA*NS + gi), q0, q1);
        gumA[gi] = bits_to_gumbel(q0 ^ q1);
      } else {
        int si = gi - NS;
        threefry2x32(k0, k1, 0u, (uint32_t)(bB*NS + si), q0, q1);
        gumB[si] = bits_to_gumbel(q0 ^ q1);
      }
    }
    __syncthreads();

    // S1: 768 weight rows, each loaded once, dots for BOTH rows
    // (per-row sequential-k chain bit-identical to r5-r15)
    if (t < 2*NH3) {
      const bool isWih = (t < NH3);
      const float4* wp = isWih
          ? (const float4*)(Wih + (size_t)t * NH)
          : (const float4*)(Whh + (size_t)(t - NH3) * NH);
      const float4* opA = isWih ? (const float4*)embA : (const float4*)hA;
      const float4* opB = isWih ? (const float4*)embB : (const float4*)hB;
      float aA = 0.f, aB = 0.f;
      #pragma unroll 8
      for (int k4 = 0; k4 < 32; ++k4) {
        float4 c = wp[k4];
        float4 vA = opA[k4], vB = opB[k4];
        aA = fmaf(c.x, vA.x, aA); aA = fmaf(c.y, vA.y, aA);
        aA = fmaf(c.z, vA.z, aA); aA = fmaf(c.w, vA.w, aA);
        aB = fmaf(c.x, vB.x, aB); aB = fmaf(c.y, vB.y, aB);
        aB = fmaf(c.z, vB.z, aB); aB = fmaf(c.w, vB.w, aB);
      }
      if (isWih) {
        giA[t] = __fadd_rn(aA, bihL[t]);
        giB[t] = __fadd_rn(aB, bihL[t]);
      } else {
        int row = t - NH3;
        ghA[row] = __fadd_rn(aA, bhhL[row]);
        ghB[row] = __fadd_rn(aB, bhhL[row]);
      }
    }
    __syncthreads();

    // S2: gates (torch r,z,n) EXACT XLA math; rowA t<128, rowB [128,256)
    if (t < NH) {
      float r = xla_sigmoidf(__fadd_rn(giA[t],      ghA[t]));
      float z = xla_sigmoidf(__fadd_rn(giA[t+NH],   ghA[t+NH]));
      float n = xla_tanhf(__fadd_rn(giA[t+2*NH], __fmul_rn(r, ghA[t+2*NH])));
      float hv = hA[t];
      hA[t] = __fadd_rn(__fmul_rn(__fsub_rn(1.0f, z), n), __fmul_rn(z, hv));
    } else if (t < 2*NH) {
      int h = t - NH;
      float r = xla_sigmoidf(__fadd_rn(giB[h],      ghB[h]));
      float z = xla_sigmoidf(__fadd_rn(giB[h+NH],   ghB[h+NH]));
      float n = xla_tanhf(__fadd_rn(giB[h+2*NH], __fmul_rn(r, ghB[h+2*NH])));
      float hv = hB[h];
      hB[h] = __fadd_rn(__fmul_rn(__fsub_rn(1.0f, z), n), __fmul_rn(z, hv));
    }
    __syncthreads();

    // S3: Hterm per row (exact chain); store SC2*(Ht+Ac) packed next to va
    if (t < NH) {
      const float4* war = (const float4*)(Wa + (size_t)t*NH3 + 2*NH);
      const float4* hn4 = (const float4*)hA;
      float acc = 0.f;
      #pragma unroll 8
      for (int k4 = 0; k4 < 32; ++k4) {
        float4 a = war[k4], hv = hn4[k4];
        acc = fmaf(a.x, hv.x, acc); acc = fmaf(a.y, hv.y, acc);
        acc = fmaf(a.z, hv.z, acc); acc = fmaf(a.w, hv.w, acc);
      }
      HtVaA[IDX2(t)].y = __fmul_rn(SC2, __fadd_rn(acc, AcL[t]));
    } else if (t < 2*NH) {
      int h = t - NH;
      const float4* war = (const float4*)(Wa + (size_t)h*NH3 + 2*NH);
      const float4* hn4 = (const float4*)hB;
      float acc = 0.f;
      #pragma unroll 8
      for (int k4 = 0; k4 < 32; ++k4) {
        float4 a = war[k4], hv = hn4[k4];
        acc = fmaf(a.x, hv.x, acc); acc = fmaf(a.y, hv.y, acc);
        acc = fmaf(a.z, hv.z, acc); acc = fmaf(a.w, hv.w, acc);
      }
      HtVaB[IDX2(h)].y = __fmul_rn(SC2, __fadd_rn(acc, AcL[h]));
    }
    __syncthreads();

    // E: attention; log2-domain energy, bare v_exp, packed {va,Ht} read
    float accE = 0.f;
    if (act) {
      #pragma unroll 4
      for (int j = 0; j < 64; ++j) {
        float4 af = AF4p[b4 + j];
        float2 hv = HtX[b2 + j];
        float e2 = fmaf(af.x, s0r, hv.y);
        e2 = fmaf(af.y, s1r, e2);
        e2 = fmaf(af.z, d0r, e2);
        e2 = fmaf(af.w, d1r, e2);
        float r = __builtin_amdgcn_rcpf(__fadd_rn(fexp2(e2), 1.0f));
        accE = fmaf(hv.x, r, accE);
      }
    }
    float accSum = __fadd_rn(accE, __shfl_xor(accE, 1));
    float sc = act ? fmaf(-2.0f, accSum, svaR) : 0.f;

    float exv = act ? __expf(sc) : 0.f;
    {
      float sm = exv;
      float c0 = __fmul_rn(exv, s0r);
      float c1 = __fmul_rn(exv, s1r);
      #pragma unroll
      for (int mm = 2; mm < 64; mm <<= 1) {
        sm = __fadd_rn(sm, __shfl_xor(sm, mm));
        c0 = __fadd_rn(c0, __shfl_xor(c0, mm));
        c1 = __fadd_rn(c1, __shfl_xor(c1, mm));
      }
      if ((t & 63) == 0) { part[w][0] = sm; part[w][1] = c0; part[w][2] = c1; }
    }
    __syncthreads();

    // F: ct2 per row; rowA from part[0..7], rowB from part[8..15]
    if (t < 2*NH) {
      int h = t & (NH - 1);
      int base = (t < NH) ? 0 : 8;
      float sume = part[base][0], r0 = part[base][1], r1 = part[base][2];
      #pragma unroll
      for (int ww = 1; ww < 8; ++ww) {
        sume = __fadd_rn(sume, part[base + ww][0]);
        r0   = __fadd_rn(r0,   part[base + ww][1]);
        r1   = __fadd_rn(r1,   part[base + ww][2]);
      }
      r0 = __fdiv_rn(r0, sume); r1 = __fdiv_rn(r1, sume);
      float4 cw = CW4[h];
      float ct2 = fmaf(r0, cw.x, fmaf(r1, cw.y, cw.z));
      if (t < NH) ct2A[IDX1(h)] = __fadd_rn(cw.w, ct2);
      else        ct2B[IDX1(h)] = __fadd_rn(cw.w, ct2);
    }
    __syncthreads();

    // G: decoder; log2-domain energy, bare v_exp; hoisted gumbel
    float accD = 0.f;
    if (act) {
      #pragma unroll 4
      for (int j = 0; j < 64; ++j) {
        float4 df = DFSp[b4 + j];
        float d2 = fmaf(df.x, s0r, ctX[b1 + j]);
        d2 = fmaf(df.y, s1r, d2);
        float r = __builtin_amdgcn_rcpf(__fadd_rn(fexp2(d2), 1.0f));
        accD = fmaf(df.z, r, accD);
      }
    }
    float accDS = __fadd_rn(accD, __shfl_xor(accD, 1));
    float sc2 = act ? fmaf(-2.0f, accDS, svdR) : 0.f;

    float e2v = act ? __expf(sc2) : 0.f;
    if (act && (tr & 1) == 0) { if (!rB) ex2A[s] = e2v; else ex2B[s] = e2v; }
    {
      float gv = -INFINITY;
      int gidx = 1 << 20;
      if (act) {
        gv = __fadd_rn(gumX[s], sc2);
        gidx = s;
      }
      float sm = e2v;
      #pragma unroll
      for (int mm = 2; mm < 64; mm <<= 1) {
        sm = __fadd_rn(sm, __shfl_xor(sm, mm));
        float ov = __shfl_xor(gv, mm); int oi = __shfl_xor(gidx, mm);
        if (ov > gv || (ov == gv && oi < gidx)) { gv = ov; gidx = oi; }
      }
      if ((t & 63) == 0) { part[w][3] = sm; part[w][4] = gv; partI[w] = gidx; }
    }
    __syncthreads();

    // A: winner per row; t==0 rowA, t==512 rowB
    if (t == 0) {
      float bv = part[0][4]; int bi = partI[0];
      float sume2 = part[0][3];
      #pragma unroll
      for (int ww = 1; ww < 8; ++ww) {
        float vv = part[ww][4]; int ii = partI[ww];
        if (vv > bv || (vv == bv && ii < bi)) { bv = vv; bi = ii; }
        sume2 = __fadd_rn(sume2, part[ww][3]);
      }
      out[(size_t)bA*NS + step] = (float)bi;
      out[(size_t)NB*NS + (size_t)bA*NS + step] = __fdiv_rn(ex2A[bi], sume2);
      xpA[0] = st0A[bi]; xpA[1] = st1A[bi];
    } else if (t == 512) {
      float bv = part[8][4]; int bi = partI[8];
      float sume2 = part[8][3];
      #pragma unroll
      for (int ww = 9; ww < 16; ++ww) {
        float vv = part[ww][4]; int ii = partI[ww];
        if (vv > bv || (vv == bv && ii < bi)) { bv = vv; bi = ii; }
        sume2 = __fadd_rn(sume2, part[ww][3]);
      }
      out[(size_t)bB*NS + step] = (float)bi;
      out[(size_t)NB*NS + (size_t)bB*NS + step] = __fdiv_rn(ex2B[bi], sume2);
      xpB[0] = st0B[bi]; xpB[1] = st1B[bi];
    }
    __syncthreads();
  }
}

// ---------------- host launch ----------------
extern "C" void kernel_launch(void* const* d_in, const int* in_sizes, int n_in,
                              void* d_out, int out_size, void* d_ws, size_t ws_size,
                              hipStream_t stream) {
  (void)in_sizes; (void)n_in; (void)out_size; (void)d_ws; (void)ws_size;
  const float* stat = (const float*)d_in[0];
  const float* dyn  = (const float*)d_in[1];
  const float* sW   = (const float*)d_in[2];
  const float* sb   = (const float*)d_in[3];
  const float* dW   = (const float*)d_in[4];
  const float* db   = (const float*)d_in[5];
  const float* x0   = (const float*)d_in[6];
  const float* h0   = (const float*)d_in[7];
  const float* Wemb = (const float*)d_in[8];
  const float* bemb = (const float*)d_in[9];
  const float* Wih  = (const float*)d_in[10];
  const float* Whh  = (const float*)d_in[11];
  const float* bih  = (const float*)d_in[12];
  const float* bhh  = (const float*)d_in[13];
  const float* Wa   = (const float*)d_in[14];
  const float* va   = (const float*)d_in[15];
  const float* Wd   = (const float*)d_in[16];
  const float* vd   = (const float*)d_in[17];
  float* out = (float*)d_out;

  k_decode<<<NB/2, NT, 0, stream>>>(stat, dyn, sW, sb, dW, db, x0, h0,
                                    Wemb, bemb, Wih, Whh, bih, bhh,
                                    Wa, va, Wd, vd, out);
}